// Round 2
// baseline (1004.306 us; speedup 1.0000x reference)
//
#include <hip/hip_runtime.h>

#define HIDDEN 1024
#define NHEADS 8
#define DIMH 128
#define NB 32
#define QLEN 128
#define VLEN 2048

typedef _Float16 half8 __attribute__((ext_vector_type(8)));
typedef _Float16 half4v __attribute__((ext_vector_type(4)));
typedef float f32x4 __attribute__((ext_vector_type(4)));

__device__ __forceinline__ void gl_lds16(const void* g, void* l) {
  __builtin_amdgcn_global_load_lds(
      (const __attribute__((address_space(1))) void*)g,
      (__attribute__((address_space(3))) void*)l, 16, 0, 0);
}

// ---- collapse conv(3)+Wloc into 4 coefficient vectors of length 128 ----
__global__ void k_coeffs(const float* __restrict__ cw, const float* __restrict__ cb,
                         const float* __restrict__ wloc, float* __restrict__ coef) {
  int d = threadIdx.x;
  if (d >= DIMH) return;
  float a0 = 0.f, a1 = 0.f, a2 = 0.f, c0 = 0.f;
  for (int c = 0; c < 10; ++c) {
    float wl = wloc[d * 10 + c];
    a0 = fmaf(wl, cw[c * 3 + 0], a0);
    a1 = fmaf(wl, cw[c * 3 + 1], a1);
    a2 = fmaf(wl, cw[c * 3 + 2], a2);
    c0 = fmaf(wl, cb[c], c0);
  }
  coef[d] = a0; coef[DIMH + d] = a1; coef[2 * DIMH + d] = a2; coef[3 * DIMH + d] = c0;
}

// ---- f32 -> f16 vectorized convert ----
__global__ void k_cvt(const float* __restrict__ in, _Float16* __restrict__ out, int n4) {
  int stride = gridDim.x * blockDim.x;
  for (int i = blockIdx.x * blockDim.x + threadIdx.x; i < n4; i += stride) {
    float4 f = reinterpret_cast<const float4*>(in)[i];
    half4v h;
    h[0] = (_Float16)f.x; h[1] = (_Float16)f.y; h[2] = (_Float16)f.z; h[3] = (_Float16)f.w;
    *reinterpret_cast<half4v*>(out + (size_t)i * 4) = h;
  }
}

// ---- NT GEMM Out[m][n] = sum_k A[m][k]*Bw[n][k] + epilogue, f16 in/out, fp32 acc ----
// mode 0: + bias_vec[n]            (qp)
// mode 1: + bias_vec[n] + loc_energy(coeffs, last_attn)   (vp)
__launch_bounds__(256, 2)
__global__ void k_gemm(const _Float16* __restrict__ A, const _Float16* __restrict__ Bw,
                       _Float16* __restrict__ Out, const float* __restrict__ bias_vec,
                       const float* __restrict__ coef, const float* __restrict__ la,
                       int mtiles, int mode) {
  __shared__ _Float16 As[128 * 32];
  __shared__ _Float16 Bs[128 * 32];
  __shared__ float sb[128];
  __shared__ float scoef[512];
  __shared__ float sla[130];

  int id = blockIdx.x;                       // grid = mtiles*8, XCD-bijective swizzle
  int id2 = (id & 7) * mtiles + (id >> 3);
  int bm = id2 >> 3;
  int bn = id2 & 7;
  const size_t m0 = (size_t)bm * 128;
  const int n0 = bn * 128;
  const int tid = threadIdx.x;
  const int l = tid & 63;
  const int w = tid >> 6;
  const int wr = w >> 1, wc = w & 1;

  if (tid < 128) sb[tid] = bias_vec[n0 + tid];
  if (mode == 1) {
    for (int i = tid; i < 512; i += 256) scoef[i] = coef[i];
    int bb = (int)(m0 >> 11);
    int vpos0 = (int)(m0 & 2047);
    size_t nla = (size_t)(bb * NHEADS + bn) * VLEN;
    for (int i = tid; i < 130; i += 256) {
      int vv = vpos0 - 1 + i;
      sla[i] = (vv >= 0 && vv < VLEN) ? la[nla + vv] : 0.f;
    }
  }

  f32x4 acc[4][4];
  const f32x4 zf = {0.f, 0.f, 0.f, 0.f};
#pragma unroll
  for (int mi = 0; mi < 4; ++mi)
#pragma unroll
    for (int ni = 0; ni < 4; ++ni) acc[mi][ni] = zf;

  const int srow = l >> 2;
  const int sch = l & 3;
  for (int k0 = 0; k0 < HIDDEN; k0 += 32) {
    __syncthreads();
#pragma unroll
    for (int i = 0; i < 2; ++i) {
      int rg = w * 2 + i;
      int row = rg * 16 + srow;
      gl_lds16(A + (m0 + row) * HIDDEN + k0 + sch * 8, &As[rg * 512]);
      gl_lds16(Bw + (size_t)(n0 + row) * HIDDEN + k0 + sch * 8, &Bs[rg * 512]);
    }
    __syncthreads();
    half8 af[4], bf[4];
#pragma unroll
    for (int mi = 0; mi < 4; ++mi)
      af[mi] = *(const half8*)&As[(wr * 64 + mi * 16 + (l & 15)) * 32 + (l >> 4) * 8];
#pragma unroll
    for (int ni = 0; ni < 4; ++ni)
      bf[ni] = *(const half8*)&Bs[(wc * 64 + ni * 16 + (l & 15)) * 32 + (l >> 4) * 8];
#pragma unroll
    for (int mi = 0; mi < 4; ++mi)
#pragma unroll
      for (int ni = 0; ni < 4; ++ni)
        acc[mi][ni] = __builtin_amdgcn_mfma_f32_16x16x32_f16(af[mi], bf[ni], acc[mi][ni], 0, 0, 0);
  }

#pragma unroll
  for (int mi = 0; mi < 4; ++mi)
#pragma unroll
    for (int ni = 0; ni < 4; ++ni)
#pragma unroll
      for (int r = 0; r < 4; ++r) {
        int row = wr * 64 + mi * 16 + (l >> 4) * 4 + r;
        int col = wc * 64 + ni * 16 + (l & 15);
        float val = acc[mi][ni][r] + sb[col];
        if (mode == 1)
          val += scoef[col] * sla[row] + scoef[128 + col] * sla[row + 1] +
                 scoef[256 + col] * sla[row + 2] + scoef[384 + col];
        Out[(m0 + row) * HIDDEN + n0 + col] = (_Float16)val;
      }
}

// ---- score[n][q][v] = qh_n . vh_n / sqrt(128), raw fp32 into attn buffer ----
__launch_bounds__(256, 2)
__global__ void k_score(const _Float16* __restrict__ qp, const _Float16* __restrict__ vp,
                        float* __restrict__ attn) {
  __shared__ _Float16 Qs[4 * 128 * 32];   // [kk][q][32]
  __shared__ _Float16 Vs[4 * 128 * 32];   // [kk][vrow][32]
  int n = blockIdx.x;
  int h = n >> 5, b = n & 31;
  const _Float16* qbase = qp + ((size_t)b * QLEN * HIDDEN + h * DIMH);
  const _Float16* vbase = vp + ((size_t)b * VLEN * HIDDEN + h * DIMH);
  float* obase = attn + (size_t)n * QLEN * VLEN;
  const int tid = threadIdx.x;
  const int l = tid & 63;
  const int w = tid >> 6;
  const int wr = w >> 1, wc = w & 1;
  const int srow = l >> 2, sch = l & 3;

  // stage Q once: wave w stages k-subtile kk=w
  for (int rg = 0; rg < 8; ++rg) {
    int row = rg * 16 + srow;
    gl_lds16(qbase + (size_t)row * HIDDEN + w * 32 + sch * 8, &Qs[w * 4096 + rg * 512]);
  }
  __syncthreads();
  half8 qa[4][4];
#pragma unroll
  for (int mi = 0; mi < 4; ++mi)
#pragma unroll
    for (int kk = 0; kk < 4; ++kk)
      qa[mi][kk] = *(const half8*)&Qs[kk * 4096 + (wr * 64 + mi * 16 + (l & 15)) * 32 + (l >> 4) * 8];

  const f32x4 zf = {0.f, 0.f, 0.f, 0.f};
  const int vt0 = blockIdx.y * 8;
  for (int vt = vt0; vt < vt0 + 8; ++vt) {
    __syncthreads();
    for (int rg = 0; rg < 8; ++rg) {
      int row = rg * 16 + srow;
      gl_lds16(vbase + (size_t)(vt * 128 + row) * HIDDEN + w * 32 + sch * 8, &Vs[w * 4096 + rg * 512]);
    }
    __syncthreads();
    f32x4 acc[4][4];
#pragma unroll
    for (int mi = 0; mi < 4; ++mi)
#pragma unroll
      for (int ni = 0; ni < 4; ++ni) acc[mi][ni] = zf;
#pragma unroll
    for (int ni = 0; ni < 4; ++ni)
#pragma unroll
      for (int kk = 0; kk < 4; ++kk) {
        half8 bv = *(const half8*)&Vs[kk * 4096 + (wc * 64 + ni * 16 + (l & 15)) * 32 + (l >> 4) * 8];
#pragma unroll
        for (int mi = 0; mi < 4; ++mi)
          acc[mi][ni] = __builtin_amdgcn_mfma_f32_16x16x32_f16(qa[mi][kk], bv, acc[mi][ni], 0, 0, 0);
      }
    const float sc = 0.08838834764831845f;
#pragma unroll
    for (int mi = 0; mi < 4; ++mi)
#pragma unroll
      for (int ni = 0; ni < 4; ++ni)
#pragma unroll
        for (int r = 0; r < 4; ++r) {
          int row = wr * 64 + mi * 16 + (l >> 4) * 4 + r;
          int col = vt * 128 + wc * 64 + ni * 16 + (l & 15);
          obase[(size_t)row * VLEN + col] = acc[mi][ni][r] * sc;
        }
  }
}

// ---- in-place row softmax: one wave per row of 2048 ----
__global__ void k_softmax(float* __restrict__ attn) {
  int row = blockIdx.x * 4 + (threadIdx.x >> 6);
  int l = threadIdx.x & 63;
  float4* p = reinterpret_cast<float4*>(attn + (size_t)row * VLEN);
  float4 x[8];
  float m = -1e30f;
#pragma unroll
  for (int i = 0; i < 8; ++i) {
    x[i] = p[l + i * 64];
    m = fmaxf(m, fmaxf(fmaxf(x[i].x, x[i].y), fmaxf(x[i].z, x[i].w)));
  }
#pragma unroll
  for (int off = 32; off; off >>= 1) m = fmaxf(m, __shfl_xor(m, off, 64));
  float s = 0.f;
#pragma unroll
  for (int i = 0; i < 8; ++i) {
    x[i].x = __expf(x[i].x - m); x[i].y = __expf(x[i].y - m);
    x[i].z = __expf(x[i].z - m); x[i].w = __expf(x[i].w - m);
    s += x[i].x + x[i].y + x[i].z + x[i].w;
  }
#pragma unroll
  for (int off = 32; off; off >>= 1) s += __shfl_xor(s, off, 64);
  float inv = 1.f / s;
#pragma unroll
  for (int i = 0; i < 8; ++i) {
    x[i].x *= inv; x[i].y *= inv; x[i].z *= inv; x[i].w *= inv;
    p[l + i * 64] = x[i];
  }
}

// ---- out_n = attn_n @ vh_n ----
__launch_bounds__(256, 2)
__global__ void k_pv(const float* __restrict__ attn, const _Float16* __restrict__ vp,
                     float* __restrict__ out) {
  __shared__ _Float16 As[128 * 32];   // attn tile f16 [q][kk]
  __shared__ _Float16 Bs[128 * 40];   // v  tile transposed [d][kk], padded stride 40
  int n = blockIdx.x;
  int h = n >> 5, b = n & 31;
  const float* abase = attn + (size_t)n * QLEN * VLEN;
  const _Float16* vbase = vp + ((size_t)b * VLEN * HIDDEN + h * DIMH);
  const int tid = threadIdx.x;
  const int l = tid & 63;
  const int w = tid >> 6;
  const int wr = w >> 1, wc = w & 1;

  f32x4 acc[4][4];
  const f32x4 zf = {0.f, 0.f, 0.f, 0.f};
#pragma unroll
  for (int mi = 0; mi < 4; ++mi)
#pragma unroll
    for (int ni = 0; ni < 4; ++ni) acc[mi][ni] = zf;

  for (int k0 = 0; k0 < VLEN; k0 += 32) {
    __syncthreads();
#pragma unroll
    for (int p = 0; p < 4; ++p) {           // attn fp32 -> f16 into As
      int q = p * 32 + (tid >> 3);
      int c4 = (tid & 7) * 4;
      float4 f = *(const float4*)&abase[(size_t)q * VLEN + k0 + c4];
      half4v hv;
      hv[0] = (_Float16)f.x; hv[1] = (_Float16)f.y; hv[2] = (_Float16)f.z; hv[3] = (_Float16)f.w;
      *(half4v*)&As[q * 32 + c4] = hv;
    }
#pragma unroll
    for (int p = 0; p < 2; ++p) {           // v tile transposed into Bs
      int kk = p * 16 + (tid >> 4);
      int d0 = (tid & 15) * 8;
      half8 wv = *(const half8*)&vbase[(size_t)(k0 + kk) * HIDDEN + d0];
#pragma unroll
      for (int i = 0; i < 8; ++i) Bs[(d0 + i) * 40 + kk] = wv[i];
    }
    __syncthreads();
    half8 af[4], bv[4];
#pragma unroll
    for (int mi = 0; mi < 4; ++mi)
      af[mi] = *(const half8*)&As[(wr * 64 + mi * 16 + (l & 15)) * 32 + (l >> 4) * 8];
#pragma unroll
    for (int ni = 0; ni < 4; ++ni)
      bv[ni] = *(const half8*)&Bs[(wc * 64 + ni * 16 + (l & 15)) * 40 + (l >> 4) * 8];
#pragma unroll
    for (int mi = 0; mi < 4; ++mi)
#pragma unroll
      for (int ni = 0; ni < 4; ++ni)
        acc[mi][ni] = __builtin_amdgcn_mfma_f32_16x16x32_f16(af[mi], bv[ni], acc[mi][ni], 0, 0, 0);
  }
#pragma unroll
  for (int mi = 0; mi < 4; ++mi)
#pragma unroll
    for (int ni = 0; ni < 4; ++ni)
#pragma unroll
      for (int r = 0; r < 4; ++r) {
        int qq = wr * 64 + mi * 16 + (l >> 4) * 4 + r;
        int dd = wc * 64 + ni * 16 + (l & 15);
        out[((size_t)b * QLEN + qq) * HIDDEN + h * DIMH + dd] = acc[mi][ni][r];
      }
}

extern "C" void kernel_launch(void* const* d_in, const int* in_sizes, int n_in,
                              void* d_out, int out_size, void* d_ws, size_t ws_size,
                              hipStream_t stream) {
  const float* q    = (const float*)d_in[0];
  const float* v    = (const float*)d_in[1];
  const float* la   = (const float*)d_in[2];
  const float* cw   = (const float*)d_in[3];
  const float* cb   = (const float*)d_in[4];
  const float* Wq   = (const float*)d_in[5];
  const float* bq   = (const float*)d_in[6];
  const float* Wv   = (const float*)d_in[7];
  const float* Wloc = (const float*)d_in[8];
  const float* bias = (const float*)d_in[9];
  float* out = (float*)d_out;
  float* attn = out + (size_t)4194304;          // B*QLEN*HIDDEN

  char* ws = (char*)d_ws;
  float* coef     = (float*)ws;                                   // 2 KB
  _Float16* Wq_h  = (_Float16*)(ws + 4096);                       // 2 MB
  _Float16* Wv_h  = (_Float16*)(ws + 4096 + (2u << 20));          // 2 MB
  _Float16* qp_h  = (_Float16*)(ws + 4096 + (4u << 20));          // 8 MB
  _Float16* vp_h  = (_Float16*)(ws + 4096 + (12u << 20));         // 134 MB
  // scratch inside the (not-yet-written) attn region of d_out:
  _Float16* v_h   = (_Float16*)attn;                              // 134 MB
  _Float16* q_h   = (_Float16*)(attn + (size_t)33554432);         // 8 MB

  k_coeffs<<<1, 128, 0, stream>>>(cw, cb, Wloc, coef);
  k_cvt<<<1024, 256, 0, stream>>>(Wq, Wq_h, 262144);
  k_cvt<<<1024, 256, 0, stream>>>(Wv, Wv_h, 262144);
  k_cvt<<<2048, 256, 0, stream>>>(q, q_h, 1048576);
  k_cvt<<<2048, 256, 0, stream>>>(v, v_h, 16777216);
  k_gemm<<<256, 256, 0, stream>>>(q_h, Wq_h, qp_h, bq, coef, la, 32, 0);
  k_gemm<<<4096, 256, 0, stream>>>(v_h, Wv_h, vp_h, bias, coef, la, 512, 1);
  k_score<<<dim3(256, 2), 256, 0, stream>>>(qp_h, vp_h, attn);
  k_softmax<<<8192, 256, 0, stream>>>(attn);
  k_pv<<<256, 256, 0, stream>>>(attn, vp_h, out);
}